// Round 3
// baseline (203.455 us; speedup 1.0000x reference)
//
#include <hip/hip_runtime.h>
#include <cstdint>
#include <cstddef>

// ---------- constants for this problem ----------
#define BATCH 2
#define SEQ   2048
#define HID   1024
#define NHEAD 16
#define DHEAD 64
#define QKV_N 3072   // 3*HID
#define NTOK  4096   // BATCH*SEQ

typedef __attribute__((ext_vector_type(4))) float f32x4;
typedef __attribute__((ext_vector_type(8))) short bf16x8;

#define QSCL 0.18033688011112042f   // (1/8) * log2(e), folded into Q at GEMM epilogue

__device__ inline unsigned short f2bf(float f) {
    union { float f; unsigned int u; } v; v.f = f;
    unsigned int u = v.u;
    unsigned int r = (u + 0x7fffu + ((u >> 16) & 1u)) >> 16;
    return (unsigned short)r;
}

__device__ __forceinline__ void gload_lds16(const void* g, void* l) {
    __builtin_amdgcn_global_load_lds(
        (const __attribute__((address_space(1))) void*)g,
        (__attribute__((address_space(3))) void*)l, 16, 0, 0);
}

// ---------- cast fp32 -> bf16 (packed ushort4) ----------
__global__ void cast_f32_bf16(const float* __restrict__ in, unsigned short* __restrict__ out, int n4) {
    int i = blockIdx.x * blockDim.x + threadIdx.x;
    if (i >= n4) return;
    float4 v = reinterpret_cast<const float4*>(in)[i];
    ushort4 o;
    o.x = f2bf(v.x); o.y = f2bf(v.y); o.z = f2bf(v.z); o.w = f2bf(v.w);
    reinterpret_cast<ushort4*>(out)[i] = o;
}

// ---------- GEMM (m97 structure): C[M][N] = A[M][K] @ B[N][K]^T + bias ----------
// tile 128x128, BK=64, 4 waves (2x2), each wave 64x64 via 4x4 frags of 16x16x32.
// global_load_lds width=16, linear LDS [128][64], 2 barriers per K-step.
// OUT_MODE: 0 = fp32 row-major; 2 = bf16 row-major with Q-scale for nn < HID.
template<int OUT_MODE>
__global__ __launch_bounds__(256) void gemm_bt(const short* __restrict__ A,
                                               const short* __restrict__ B,
                                               const float* __restrict__ bias,
                                               void* __restrict__ Cout,
                                               int M, int N, int K) {
    __shared__ short sA[128 * 64];
    __shared__ short sB[128 * 64];
    const int tid  = threadIdx.x;
    const int lane = tid & 63;
    const int wave = tid >> 6;
    const int wm = wave >> 1, wn = wave & 1;
    const int m0 = blockIdx.y * 128;
    const int n0 = blockIdx.x * 128;

    f32x4 acc[4][4];
    #pragma unroll
    for (int i = 0; i < 4; ++i)
        #pragma unroll
        for (int j = 0; j < 4; ++j) acc[i][j] = (f32x4){0.f, 0.f, 0.f, 0.f};

    const int r  = lane & 15;
    const int ko = (lane >> 4) * 8;
    const int srow = lane >> 3;   // 0..7 within 8-row chunk
    const int sgr  = lane & 7;    // 16B granule within row

    for (int kt = 0; kt < K; kt += 64) {
        __syncthreads();
        #pragma unroll
        for (int i = 0; i < 4; ++i) {
            const int c = wave * 4 + i;                   // chunk 0..15 (8 rows each)
            gload_lds16(A + (size_t)(m0 + c * 8 + srow) * K + kt + sgr * 8, &sA[c * 512]);
            gload_lds16(B + (size_t)(n0 + c * 8 + srow) * K + kt + sgr * 8, &sB[c * 512]);
        }
        __syncthreads();

        #pragma unroll
        for (int kk = 0; kk < 2; ++kk) {
            bf16x8 af[4], bfr[4];
            #pragma unroll
            for (int i = 0; i < 4; ++i) {
                af[i]  = *reinterpret_cast<const bf16x8*>(&sA[(wm * 64 + i * 16 + r) * 64 + kk * 32 + ko]);
                bfr[i] = *reinterpret_cast<const bf16x8*>(&sB[(wn * 64 + i * 16 + r) * 64 + kk * 32 + ko]);
            }
            #pragma unroll
            for (int i = 0; i < 4; ++i)
                #pragma unroll
                for (int j = 0; j < 4; ++j)
                    acc[i][j] = __builtin_amdgcn_mfma_f32_16x16x32_bf16(af[i], bfr[j], acc[i][j], 0, 0, 0);
        }
    }

    // epilogue: D layout col=lane&15, row=4*(lane>>4)+reg
    const int col_l = lane & 15;
    const int row_g = (lane >> 4) * 4;
    #pragma unroll
    for (int i = 0; i < 4; ++i) {
        #pragma unroll
        for (int j = 0; j < 4; ++j) {
            int nn = n0 + wn * 64 + j * 16 + col_l;
            float bv = bias[nn];
            float scl = (OUT_MODE == 2 && nn < HID) ? QSCL : 1.0f;
            #pragma unroll
            for (int reg = 0; reg < 4; ++reg) {
                int mm = m0 + wm * 64 + i * 16 + row_g + reg;
                float v = (acc[i][j][reg] + bv) * scl;
                if (OUT_MODE == 0) {
                    reinterpret_cast<float*>(Cout)[(size_t)mm * N + nn] = v;
                } else {
                    reinterpret_cast<unsigned short*>(Cout)[(size_t)mm * N + nn] = f2bf(v);
                }
            }
        }
    }
}

// ---------- transpose V part of qkv -> vT [bh][d][s] ----------
#define TLDP 72
__global__ __launch_bounds__(256) void transpose_v(const short* __restrict__ qkv,
                                                   short* __restrict__ vT) {
    const int st = blockIdx.x;   // s-tile (64 tokens)
    const int bh = blockIdx.y;
    const int b  = bh >> 4, h = bh & 15;
    __shared__ short ld[64 * TLDP];
    const int tid = threadIdx.x;

    #pragma unroll
    for (int i = 0; i < 2; ++i) {
        int idx = i * 256 + tid;          // 0..511
        int row = idx >> 3, c = idx & 7;
        int4 v = *reinterpret_cast<const int4*>(
            qkv + ((size_t)(b * SEQ + st * 64 + row)) * QKV_N + 2 * HID + h * DHEAD + c * 8);
        *reinterpret_cast<int4*>(&ld[row * TLDP + c * 8]) = v;
    }
    __syncthreads();
    #pragma unroll
    for (int i = 0; i < 4; ++i) {
        int idx = i * 256 + tid;          // 0..1023
        int d = idx >> 4, sc = idx & 15;  // d row, 4-token chunk
        ushort4 o;
        o.x = (unsigned short)ld[(sc * 4 + 0) * TLDP + d];
        o.y = (unsigned short)ld[(sc * 4 + 1) * TLDP + d];
        o.z = (unsigned short)ld[(sc * 4 + 2) * TLDP + d];
        o.w = (unsigned short)ld[(sc * 4 + 3) * TLDP + d];
        *reinterpret_cast<ushort4*>(&vT[((size_t)(bh * DHEAD + d)) * SEQ + st * 64 + sc * 4]) = o;
    }
}

// ---------- flash attention (causal), bf16 MFMA, no-max softmax ----------
// grid (32, 32): qt = (31 - x + y) & 31 (late blocks get small qt -> short tail).
// Block = 128 threads = 2 waves, each wave 32 q-rows. KV tile = 64, reg-prefetched.
#define KLDP 72  // LDS pitch (64 + 8 pad)

__global__ __launch_bounds__(128) void attn_fwd(const short* __restrict__ qkv,
                                                const short* __restrict__ vT,
                                                short* __restrict__ av) {
    const int bh = blockIdx.y;
    const int b  = bh >> 4;
    const int h  = bh & 15;
    const int qt = (31 - blockIdx.x + blockIdx.y) & 31;

    __shared__ short sK [64 * KLDP];       // K tile  [kv][d]
    __shared__ short sVT[64 * KLDP];       // V^T tile [d][kv]
    __shared__ short sP [2][32 * KLDP];    // per-wave P tile [row][kv]

    const int tid  = threadIdx.x;          // 0..127
    const int lane = tid & 63;
    const int wave = tid >> 6;
    const int r    = lane & 15;
    const int G    = lane >> 4;
    const int ko   = G * 8;
    const int row_g = G * 4;

    const int qbw = qt * 64 + wave * 32;

    // Q fragments (pre-scaled by QSCL in the GEMM epilogue)
    bf16x8 qf[2][2];
    #pragma unroll
    for (int mi = 0; mi < 2; ++mi) {
        const short* Qg = qkv + ((size_t)(b * SEQ + qbw + mi * 16 + r)) * QKV_N + h * DHEAD;
        qf[mi][0] = *reinterpret_cast<const bf16x8*>(Qg + ko);
        qf[mi][1] = *reinterpret_cast<const bf16x8*>(Qg + 32 + ko);
    }

    f32x4 oacc[2][4];
    f32x4 oL[2];
    #pragma unroll
    for (int mi = 0; mi < 2; ++mi) {
        oL[mi] = (f32x4){0.f, 0.f, 0.f, 0.f};
        #pragma unroll
        for (int dg = 0; dg < 4; ++dg) oacc[mi][dg] = (f32x4){0.f, 0.f, 0.f, 0.f};
    }

    bf16x8 ones;
    #pragma unroll
    for (int e = 0; e < 8; ++e) ones[e] = (short)0x3f80;   // bf16 1.0

    // staging map: chunk i (i<4): row = i*16 + (tid>>3), granule = tid&7
    const int prow = tid >> 3;    // 0..15
    const int pc   = tid & 7;

    // prefetch tile 0
    int4 kreg[4], vreg[4];
    #pragma unroll
    for (int i = 0; i < 4; ++i) {
        int row = i * 16 + prow;
        kreg[i] = *reinterpret_cast<const int4*>(
            qkv + ((size_t)(b * SEQ + row)) * QKV_N + HID + h * DHEAD + pc * 8);
        vreg[i] = *reinterpret_cast<const int4*>(
            vT + ((size_t)(bh * DHEAD + row)) * SEQ + pc * 8);
    }

    for (int t = 0; t <= qt; ++t) {
        const int kv0 = t * 64;
        __syncthreads();
        #pragma unroll
        for (int i = 0; i < 4; ++i) {
            int row = i * 16 + prow;
            *reinterpret_cast<int4*>(&sK [row * KLDP + pc * 8]) = kreg[i];
            *reinterpret_cast<int4*>(&sVT[row * KLDP + pc * 8]) = vreg[i];
        }
        if (t < qt) {
            const int kvn = kv0 + 64;
            #pragma unroll
            for (int i = 0; i < 4; ++i) {
                int row = i * 16 + prow;
                kreg[i] = *reinterpret_cast<const int4*>(
                    qkv + ((size_t)(b * SEQ + kvn + row)) * QKV_N + HID + h * DHEAD + pc * 8);
                vreg[i] = *reinterpret_cast<const int4*>(
                    vT + ((size_t)(bh * DHEAD + row)) * SEQ + kvn + pc * 8);
            }
        }
        __syncthreads();

        // K fragments (shared between both mi)
        bf16x8 kb[4][2];
        #pragma unroll
        for (int g = 0; g < 4; ++g) {
            kb[g][0] = *reinterpret_cast<const bf16x8*>(&sK[(g * 16 + r) * KLDP + ko]);
            kb[g][1] = *reinterpret_cast<const bf16x8*>(&sK[(g * 16 + r) * KLDP + 32 + ko]);
        }

        const bool diag = (t == qt);

        #pragma unroll
        for (int mi = 0; mi < 2; ++mi) {
            f32x4 s[4];
            #pragma unroll
            for (int g = 0; g < 4; ++g) {
                f32x4 z = (f32x4){0.f, 0.f, 0.f, 0.f};
                z = __builtin_amdgcn_mfma_f32_16x16x32_bf16(qf[mi][0], kb[g][0], z, 0, 0, 0);
                z = __builtin_amdgcn_mfma_f32_16x16x32_bf16(qf[mi][1], kb[g][1], z, 0, 0, 0);
                s[g] = z;
            }
            if (diag) {
                #pragma unroll
                for (int g = 0; g < 4; ++g) {
                    #pragma unroll
                    for (int reg = 0; reg < 4; ++reg) {
                        int kvg = g * 16 + r;                       // D col = lane&15
                        int qg  = wave * 32 + mi * 16 + row_g + reg;// D row (within q-tile)
                        if (kvg > qg) s[g][reg] = -30000.f;
                    }
                }
            }
            // P = exp2(S) (Q pre-scaled; no max subtraction -- fp32 range suffices)
            #pragma unroll
            for (int g = 0; g < 4; ++g) {
                #pragma unroll
                for (int reg = 0; reg < 4; ++reg) {
                    float p = __builtin_amdgcn_exp2f(s[g][reg]);
                    sP[wave][(mi * 16 + row_g + reg) * KLDP + g * 16 + r] = (short)f2bf(p);
                }
            }
        }

        asm volatile("s_waitcnt lgkmcnt(0)" ::: "memory");
        __builtin_amdgcn_sched_barrier(0);

        bf16x8 vb[4][2];
        #pragma unroll
        for (int dg = 0; dg < 4; ++dg) {
            vb[dg][0] = *reinterpret_cast<const bf16x8*>(&sVT[(dg * 16 + r) * KLDP + ko]);
            vb[dg][1] = *reinterpret_cast<const bf16x8*>(&sVT[(dg * 16 + r) * KLDP + 32 + ko]);
        }

        #pragma unroll
        for (int mi = 0; mi < 2; ++mi) {
            bf16x8 pa0 = *reinterpret_cast<const bf16x8*>(&sP[wave][(mi * 16 + r) * KLDP + ko]);
            bf16x8 pa1 = *reinterpret_cast<const bf16x8*>(&sP[wave][(mi * 16 + r) * KLDP + 32 + ko]);
            #pragma unroll
            for (int dg = 0; dg < 4; ++dg) {
                oacc[mi][dg] = __builtin_amdgcn_mfma_f32_16x16x32_bf16(pa0, vb[dg][0], oacc[mi][dg], 0, 0, 0);
                oacc[mi][dg] = __builtin_amdgcn_mfma_f32_16x16x32_bf16(pa1, vb[dg][1], oacc[mi][dg], 0, 0, 0);
            }
            oL[mi] = __builtin_amdgcn_mfma_f32_16x16x32_bf16(pa0, ones, oL[mi], 0, 0, 0);
            oL[mi] = __builtin_amdgcn_mfma_f32_16x16x32_bf16(pa1, ones, oL[mi], 0, 0, 0);
        }
    }

    // normalize and write AV (bf16)
    #pragma unroll
    for (int mi = 0; mi < 2; ++mi) {
        float il[4];
        #pragma unroll
        for (int reg = 0; reg < 4; ++reg) il[reg] = 1.0f / oL[mi][reg];
        #pragma unroll
        for (int dg = 0; dg < 4; ++dg) {
            #pragma unroll
            for (int reg = 0; reg < 4; ++reg) {
                float v = oacc[mi][dg][reg] * il[reg];
                size_t tok = (size_t)(b * SEQ + qbw + mi * 16 + row_g + reg);
                av[tok * HID + h * DHEAD + dg * 16 + r] = (short)f2bf(v);
            }
        }
    }
}

extern "C" void kernel_launch(void* const* d_in, const int* in_sizes, int n_in,
                              void* d_out, int out_size, void* d_ws, size_t ws_size,
                              hipStream_t stream) {
    const float* x     = (const float*)d_in[0];
    const float* W_qkv = (const float*)d_in[1];
    const float* b_qkv = (const float*)d_in[2];
    const float* W_o   = (const float*)d_in[3];
    const float* b_o   = (const float*)d_in[4];
    float* out = (float*)d_out;

    const int n_x    = NTOK * HID;
    const int n_wqkv = QKV_N * HID;
    const int n_wo   = HID * HID;
    const int n_qkv  = NTOK * QKV_N;
    const int n_av   = NTOK * HID;

    short* xb    = (short*)d_ws;
    short* wqkvb = xb + n_x;
    short* wob   = wqkvb + n_wqkv;
    short* qkv   = wob + n_wo;
    short* av    = qkv + n_qkv;
    short* vT    = av + n_av;

    cast_f32_bf16<<<n_x / 1024,    256, 0, stream>>>(x,     (unsigned short*)xb,    n_x / 4);
    cast_f32_bf16<<<n_wqkv / 1024, 256, 0, stream>>>(W_qkv, (unsigned short*)wqkvb, n_wqkv / 4);
    cast_f32_bf16<<<n_wo / 1024,   256, 0, stream>>>(W_o,   (unsigned short*)wob,   n_wo / 4);

    // qkv = x @ W_qkv^T + b_qkv  -> bf16 [4096][3072], Q columns pre-scaled by QSCL
    gemm_bt<2><<<dim3(QKV_N / 128, NTOK / 128), 256, 0, stream>>>(
        xb, wqkvb, b_qkv, (void*)qkv, NTOK, QKV_N, HID);

    // vT [32 bh][64 d][2048 s]
    transpose_v<<<dim3(SEQ / 64, BATCH * NHEAD), 256, 0, stream>>>(qkv, vT);

    // attention -> av bf16 [4096][1024]
    attn_fwd<<<dim3(32, 32), 128, 0, stream>>>(qkv, vT, av);

    // out = av @ W_o^T + b_o  -> fp32
    gemm_bt<0><<<dim3(HID / 128, NTOK / 128), 256, 0, stream>>>(
        av, wob, b_o, (void*)out, NTOK, HID, HID);
}

// Round 4
// 147.529 us; speedup vs baseline: 1.3791x; 1.3791x over previous
//
#include <hip/hip_runtime.h>
#include <cstdint>
#include <cstddef>

// ---------- constants for this problem ----------
#define BATCH 2
#define SEQ   2048
#define HID   1024
#define NHEAD 16
#define DHEAD 64
#define QKV_N 3072   // 3*HID
#define NTOK  4096   // BATCH*SEQ

typedef __attribute__((ext_vector_type(4))) float f32x4;
typedef __attribute__((ext_vector_type(8))) short bf16x8;

#define QSCL 0.18033688011112042f   // (1/8) * log2(e), folded into Q at GEMM epilogue

__device__ inline unsigned short f2bf(float f) {
    union { float f; unsigned int u; } v; v.f = f;
    unsigned int u = v.u;
    unsigned int r = (u + 0x7fffu + ((u >> 16) & 1u)) >> 16;
    return (unsigned short)r;
}

__device__ __forceinline__ void gload_lds16(const void* g, void* l) {
    __builtin_amdgcn_global_load_lds(
        (const __attribute__((address_space(1))) void*)g,
        (__attribute__((address_space(3))) void*)l, 16, 0, 0);
}

// ---------- cast fp32 -> bf16 (packed ushort4) ----------
__global__ void cast_f32_bf16(const float* __restrict__ in, unsigned short* __restrict__ out, int n4) {
    int i = blockIdx.x * blockDim.x + threadIdx.x;
    if (i >= n4) return;
    float4 v = reinterpret_cast<const float4*>(in)[i];
    ushort4 o;
    o.x = f2bf(v.x); o.y = f2bf(v.y); o.z = f2bf(v.z); o.w = f2bf(v.w);
    reinterpret_cast<ushort4*>(out)[i] = o;
}

// ---------- GEMM (m97 structure): C[M][N] = A[M][K] @ B[N][K]^T + bias ----------
// tile 128x128, BK=64, 4 waves (2x2), each wave 64x64 via 4x4 frags of 16x16x32.
// global_load_lds width=16, linear LDS [128][64], 2 barriers per K-step.
// OUT_MODE: 0 = fp32 row-major; 2 = bf16 row-major with Q-scale for nn < HID.
template<int OUT_MODE>
__global__ __launch_bounds__(256) void gemm_bt(const short* __restrict__ A,
                                               const short* __restrict__ B,
                                               const float* __restrict__ bias,
                                               void* __restrict__ Cout,
                                               int M, int N, int K) {
    __shared__ short sA[128 * 64];
    __shared__ short sB[128 * 64];
    const int tid  = threadIdx.x;
    const int lane = tid & 63;
    const int wave = tid >> 6;
    const int wm = wave >> 1, wn = wave & 1;
    const int m0 = blockIdx.y * 128;
    const int n0 = blockIdx.x * 128;

    f32x4 acc[4][4];
    #pragma unroll
    for (int i = 0; i < 4; ++i)
        #pragma unroll
        for (int j = 0; j < 4; ++j) acc[i][j] = (f32x4){0.f, 0.f, 0.f, 0.f};

    const int r  = lane & 15;
    const int ko = (lane >> 4) * 8;
    const int srow = lane >> 3;   // 0..7 within 8-row chunk
    const int sgr  = lane & 7;    // 16B granule within row

    for (int kt = 0; kt < K; kt += 64) {
        __syncthreads();
        #pragma unroll
        for (int i = 0; i < 4; ++i) {
            const int c = wave * 4 + i;                   // chunk 0..15 (8 rows each)
            gload_lds16(A + (size_t)(m0 + c * 8 + srow) * K + kt + sgr * 8, &sA[c * 512]);
            gload_lds16(B + (size_t)(n0 + c * 8 + srow) * K + kt + sgr * 8, &sB[c * 512]);
        }
        __syncthreads();

        #pragma unroll
        for (int kk = 0; kk < 2; ++kk) {
            bf16x8 af[4], bfr[4];
            #pragma unroll
            for (int i = 0; i < 4; ++i) {
                af[i]  = *reinterpret_cast<const bf16x8*>(&sA[(wm * 64 + i * 16 + r) * 64 + kk * 32 + ko]);
                bfr[i] = *reinterpret_cast<const bf16x8*>(&sB[(wn * 64 + i * 16 + r) * 64 + kk * 32 + ko]);
            }
            #pragma unroll
            for (int i = 0; i < 4; ++i)
                #pragma unroll
                for (int j = 0; j < 4; ++j)
                    acc[i][j] = __builtin_amdgcn_mfma_f32_16x16x32_bf16(af[i], bfr[j], acc[i][j], 0, 0, 0);
        }
    }

    // epilogue: D layout col=lane&15, row=4*(lane>>4)+reg
    const int col_l = lane & 15;
    const int row_g = (lane >> 4) * 4;
    #pragma unroll
    for (int i = 0; i < 4; ++i) {
        #pragma unroll
        for (int j = 0; j < 4; ++j) {
            int nn = n0 + wn * 64 + j * 16 + col_l;
            float bv = bias[nn];
            float scl = (OUT_MODE == 2 && nn < HID) ? QSCL : 1.0f;
            #pragma unroll
            for (int reg = 0; reg < 4; ++reg) {
                int mm = m0 + wm * 64 + i * 16 + row_g + reg;
                float v = (acc[i][j][reg] + bv) * scl;
                if (OUT_MODE == 0) {
                    reinterpret_cast<float*>(Cout)[(size_t)mm * N + nn] = v;
                } else {
                    reinterpret_cast<unsigned short*>(Cout)[(size_t)mm * N + nn] = f2bf(v);
                }
            }
        }
    }
}

// ---------- transpose V part of qkv -> vT [bh][d][s] ----------
#define TLDP 72
__global__ __launch_bounds__(256) void transpose_v(const short* __restrict__ qkv,
                                                   short* __restrict__ vT) {
    const int st = blockIdx.x;   // s-tile (64 tokens)
    const int bh = blockIdx.y;
    const int b  = bh >> 4, h = bh & 15;
    __shared__ short ld[64 * TLDP];
    const int tid = threadIdx.x;

    #pragma unroll
    for (int i = 0; i < 2; ++i) {
        int idx = i * 256 + tid;          // 0..511
        int row = idx >> 3, c = idx & 7;
        int4 v = *reinterpret_cast<const int4*>(
            qkv + ((size_t)(b * SEQ + st * 64 + row)) * QKV_N + 2 * HID + h * DHEAD + c * 8);
        *reinterpret_cast<int4*>(&ld[row * TLDP + c * 8]) = v;
    }
    __syncthreads();
    #pragma unroll
    for (int i = 0; i < 4; ++i) {
        int idx = i * 256 + tid;          // 0..1023
        int d = idx >> 4, sc = idx & 15;  // d row, 4-token chunk
        ushort4 o;
        o.x = (unsigned short)ld[(sc * 4 + 0) * TLDP + d];
        o.y = (unsigned short)ld[(sc * 4 + 1) * TLDP + d];
        o.z = (unsigned short)ld[(sc * 4 + 2) * TLDP + d];
        o.w = (unsigned short)ld[(sc * 4 + 3) * TLDP + d];
        *reinterpret_cast<ushort4*>(&vT[((size_t)(bh * DHEAD + d)) * SEQ + st * 64 + sc * 4]) = o;
    }
}

// ---------- flash attention (causal), bf16 MFMA, no-max softmax ----------
// grid (32, 32): qt = (31 - x + y) & 31 (early-dispatched blocks get large qt).
// Block = 128 threads = 2 waves, each wave 32 q-rows. KV tile = 64.
// K/V double-buffered in LDS via global_load_lds with XOR-swizzled SOURCE
// (rule #21: linear LDS dest + inverse-swizzled global src + swizzled read).
// LDS = 16K + 16K + 8K = 40960 B exactly -> 4 blocks/CU.
#define SWZ(g_, row_) ((g_) ^ ((row_) & 7))

__global__ __launch_bounds__(128, 2) void attn_fwd(const short* __restrict__ qkv,
                                                   const short* __restrict__ vT,
                                                   short* __restrict__ av) {
    const int bh = blockIdx.y;
    const int b  = bh >> 4;
    const int h  = bh & 15;
    const int qt = (31 - blockIdx.x + blockIdx.y) & 31;

    __shared__ short sK [2][64 * 64];   // [buf][kv][d]   linear, source-swizzled
    __shared__ short sVT[2][64 * 64];   // [buf][d][kv]   linear, source-swizzled
    __shared__ short sP [2][32 * 64];   // [wave][row][kv] swizzled columns

    const int tid  = threadIdx.x;          // 0..127
    const int lane = tid & 63;
    const int wave = tid >> 6;
    const int r    = lane & 15;
    const int G    = lane >> 4;
    const int row_g = G * 4;

    const int qbw = qt * 64 + wave * 32;

    // Q fragments (pre-scaled by QSCL in the GEMM epilogue)
    bf16x8 qf[2][2];
    #pragma unroll
    for (int mi = 0; mi < 2; ++mi) {
        const short* Qg = qkv + ((size_t)(b * SEQ + qbw + mi * 16 + r)) * QKV_N + h * DHEAD;
        qf[mi][0] = *reinterpret_cast<const bf16x8*>(Qg + G * 8);
        qf[mi][1] = *reinterpret_cast<const bf16x8*>(Qg + 32 + G * 8);
    }

    f32x4 oacc[2][4];
    f32x4 oL[2];
    #pragma unroll
    for (int mi = 0; mi < 2; ++mi) {
        oL[mi] = (f32x4){0.f, 0.f, 0.f, 0.f};
        #pragma unroll
        for (int dg = 0; dg < 4; ++dg) oacc[mi][dg] = (f32x4){0.f, 0.f, 0.f, 0.f};
    }

    bf16x8 ones;
    #pragma unroll
    for (int e = 0; e < 8; ++e) ones[e] = (short)0x3f80;   // bf16 1.0

    // staging: wave handles granules [i*128 + wave*64 + lane], i=0..3 (K and V^T)
    const int lrow = lane >> 3;   // row offset within 8-row lane group
    const int lsg  = lane & 7;    // linear granule within row

    #define STAGE(kv0_, buf_)                                                              \
        {                                                                                  \
            _Pragma("unroll")                                                              \
            for (int i = 0; i < 4; ++i) {                                                  \
                int row  = i * 16 + wave * 8 + lrow;                                       \
                int srcg = lsg ^ (row & 7);                                                \
                gload_lds16(qkv + (size_t)(b * SEQ + (kv0_) + row) * QKV_N                 \
                                + HID + h * DHEAD + srcg * 8,                              \
                            &sK[buf_][(i * 128 + wave * 64) * 8]);                         \
                gload_lds16(vT + (size_t)(bh * DHEAD + row) * SEQ + (kv0_) + srcg * 8,     \
                            &sVT[buf_][(i * 128 + wave * 64) * 8]);                        \
            }                                                                              \
        }

    STAGE(0, 0);
    __syncthreads();   // implicit vmcnt(0) drain: tile 0 landed
    int cur = 0;

    for (int t = 0; t <= qt; ++t) {
        if (t < qt) STAGE((t + 1) * 64, cur ^ 1);   // async prefetch, no wait

        // K fragments (swizzled read)
        bf16x8 kb[4][2];
        #pragma unroll
        for (int g = 0; g < 4; ++g) {
            int row = g * 16 + r;
            kb[g][0] = *reinterpret_cast<const bf16x8*>(&sK[cur][row * 64 + SWZ(G, row) * 8]);
            kb[g][1] = *reinterpret_cast<const bf16x8*>(&sK[cur][row * 64 + SWZ(4 + G, row) * 8]);
        }

        const bool diag = (t == qt);

        #pragma unroll
        for (int mi = 0; mi < 2; ++mi) {
            f32x4 s[4];
            #pragma unroll
            for (int g = 0; g < 4; ++g) {
                f32x4 z = (f32x4){0.f, 0.f, 0.f, 0.f};
                z = __builtin_amdgcn_mfma_f32_16x16x32_bf16(qf[mi][0], kb[g][0], z, 0, 0, 0);
                z = __builtin_amdgcn_mfma_f32_16x16x32_bf16(qf[mi][1], kb[g][1], z, 0, 0, 0);
                s[g] = z;
            }
            if (diag) {
                #pragma unroll
                for (int g = 0; g < 4; ++g) {
                    #pragma unroll
                    for (int reg = 0; reg < 4; ++reg) {
                        int kvg = g * 16 + r;                        // D col = lane&15
                        int qg  = wave * 32 + mi * 16 + row_g + reg; // D row (within q-tile)
                        if (kvg > qg) s[g][reg] = -30000.f;
                    }
                }
            }
            // P = exp2(S) -> bf16 -> sP, column-granule swizzled
            #pragma unroll
            for (int g = 0; g < 4; ++g) {
                int gc = g * 2 + (r >> 3);     // linear granule of column g*16+r
                #pragma unroll
                for (int reg = 0; reg < 4; ++reg) {
                    float p = __builtin_amdgcn_exp2f(s[g][reg]);
                    int row = mi * 16 + row_g + reg;
                    sP[wave][row * 64 + SWZ(gc, row) * 8 + (r & 7)] = (short)f2bf(p);
                }
            }
        }

        asm volatile("s_waitcnt lgkmcnt(0)" ::: "memory");
        __builtin_amdgcn_sched_barrier(0);

        // V fragments (swizzled read)
        bf16x8 vb[4][2];
        #pragma unroll
        for (int dg = 0; dg < 4; ++dg) {
            int row = dg * 16 + r;
            vb[dg][0] = *reinterpret_cast<const bf16x8*>(&sVT[cur][row * 64 + SWZ(G, row) * 8]);
            vb[dg][1] = *reinterpret_cast<const bf16x8*>(&sVT[cur][row * 64 + SWZ(4 + G, row) * 8]);
        }

        #pragma unroll
        for (int mi = 0; mi < 2; ++mi) {
            int prow = mi * 16 + r;
            bf16x8 pa0 = *reinterpret_cast<const bf16x8*>(&sP[wave][prow * 64 + SWZ(G, prow) * 8]);
            bf16x8 pa1 = *reinterpret_cast<const bf16x8*>(&sP[wave][prow * 64 + SWZ(4 + G, prow) * 8]);
            #pragma unroll
            for (int dg = 0; dg < 4; ++dg) {
                oacc[mi][dg] = __builtin_amdgcn_mfma_f32_16x16x32_bf16(pa0, vb[dg][0], oacc[mi][dg], 0, 0, 0);
                oacc[mi][dg] = __builtin_amdgcn_mfma_f32_16x16x32_bf16(pa1, vb[dg][1], oacc[mi][dg], 0, 0, 0);
            }
            oL[mi] = __builtin_amdgcn_mfma_f32_16x16x32_bf16(pa0, ones, oL[mi], 0, 0, 0);
            oL[mi] = __builtin_amdgcn_mfma_f32_16x16x32_bf16(pa1, ones, oL[mi], 0, 0, 0);
        }

        __syncthreads();   // implicit vmcnt drain: next tile landed; sK/sVT[cur] free
        cur ^= 1;
    }

    // normalize and write AV (bf16)
    #pragma unroll
    for (int mi = 0; mi < 2; ++mi) {
        float il[4];
        #pragma unroll
        for (int reg = 0; reg < 4; ++reg) il[reg] = 1.0f / oL[mi][reg];
        #pragma unroll
        for (int dg = 0; dg < 4; ++dg) {
            #pragma unroll
            for (int reg = 0; reg < 4; ++reg) {
                float v = oacc[mi][dg][reg] * il[reg];
                size_t tok = (size_t)(b * SEQ + qbw + mi * 16 + row_g + reg);
                av[tok * HID + h * DHEAD + dg * 16 + r] = (short)f2bf(v);
            }
        }
    }
}

extern "C" void kernel_launch(void* const* d_in, const int* in_sizes, int n_in,
                              void* d_out, int out_size, void* d_ws, size_t ws_size,
                              hipStream_t stream) {
    const float* x     = (const float*)d_in[0];
    const float* W_qkv = (const float*)d_in[1];
    const float* b_qkv = (const float*)d_in[2];
    const float* W_o   = (const float*)d_in[3];
    const float* b_o   = (const float*)d_in[4];
    float* out = (float*)d_out;

    const int n_x    = NTOK * HID;
    const int n_wqkv = QKV_N * HID;
    const int n_wo   = HID * HID;
    const int n_qkv  = NTOK * QKV_N;
    const int n_av   = NTOK * HID;

    short* xb    = (short*)d_ws;
    short* wqkvb = xb + n_x;
    short* wob   = wqkvb + n_wqkv;
    short* qkv   = wob + n_wo;
    short* av    = qkv + n_qkv;
    short* vT    = av + n_av;

    cast_f32_bf16<<<n_x / 1024,    256, 0, stream>>>(x,     (unsigned short*)xb,    n_x / 4);
    cast_f32_bf16<<<n_wqkv / 1024, 256, 0, stream>>>(W_qkv, (unsigned short*)wqkvb, n_wqkv / 4);
    cast_f32_bf16<<<n_wo / 1024,   256, 0, stream>>>(W_o,   (unsigned short*)wob,   n_wo / 4);

    // qkv = x @ W_qkv^T + b_qkv  -> bf16 [4096][3072], Q columns pre-scaled by QSCL
    gemm_bt<2><<<dim3(QKV_N / 128, NTOK / 128), 256, 0, stream>>>(
        xb, wqkvb, b_qkv, (void*)qkv, NTOK, QKV_N, HID);

    // vT [32 bh][64 d][2048 s]
    transpose_v<<<dim3(SEQ / 64, BATCH * NHEAD), 256, 0, stream>>>(qkv, vT);

    // attention -> av bf16 [4096][1024]
    attn_fwd<<<dim3(32, 32), 128, 0, stream>>>(qkv, vT, av);

    // out = av @ W_o^T + b_o  -> fp32
    gemm_bt<0><<<dim3(HID / 128, NTOK / 128), 256, 0, stream>>>(
        av, wob, b_o, (void*)out, NTOK, HID, HID);
}

// Round 5
// 128.742 us; speedup vs baseline: 1.5803x; 1.1459x over previous
//
#include <hip/hip_runtime.h>
#include <cstdint>
#include <cstddef>

// ---------- constants for this problem ----------
#define BATCH 2
#define SEQ   2048
#define HID   1024
#define NHEAD 16
#define DHEAD 64
#define QKV_N 3072   // 3*HID
#define NTOK  4096   // BATCH*SEQ

typedef __attribute__((ext_vector_type(4))) float f32x4;
typedef __attribute__((ext_vector_type(8))) short bf16x8;

#define QSCL 0.18033688011112042f   // (1/8) * log2(e), folded into Q at GEMM epilogue

__device__ inline unsigned short f2bf(float f) {
    union { float f; unsigned int u; } v; v.f = f;
    unsigned int u = v.u;
    unsigned int r = (u + 0x7fffu + ((u >> 16) & 1u)) >> 16;
    return (unsigned short)r;
}

__device__ __forceinline__ void gload_lds16(const void* g, void* l) {
    __builtin_amdgcn_global_load_lds(
        (const __attribute__((address_space(1))) void*)g,
        (__attribute__((address_space(3))) void*)l, 16, 0, 0);
}

// ---------- cast fp32 -> bf16 (packed ushort4) ----------
__global__ void cast_f32_bf16(const float* __restrict__ in, unsigned short* __restrict__ out, int n4) {
    int i = blockIdx.x * blockDim.x + threadIdx.x;
    if (i >= n4) return;
    float4 v = reinterpret_cast<const float4*>(in)[i];
    ushort4 o;
    o.x = f2bf(v.x); o.y = f2bf(v.y); o.z = f2bf(v.z); o.w = f2bf(v.w);
    reinterpret_cast<ushort4*>(out)[i] = o;
}

// ---------- GEMM, 2-phase dbuf pipeline: C[M][N] = A[M][K] @ B[N][K]^T + bias ----------
// tile 128xBN, BK=32, double-buffered LDS staged by global_load_lds (prefetch next
// K-tile BEFORE computing current; ONE barrier per step -> load latency hidden under
// compute). Granule XOR-swizzle on both source and read (involution, rule #21).
// 4 waves (2x2), each wave 64 x BN/2. XCD-aware 1D grid swizzle.
// OUT_MODE: 0 = fp32 row-major; 2 = bf16 row-major with Q-scale for nn < HID.
template<int BN, int OUT_MODE>
__global__ __launch_bounds__(256) void gemm_bt(const short* __restrict__ A,
                                               const short* __restrict__ B,
                                               const float* __restrict__ bias,
                                               void* __restrict__ Cout,
                                               int M, int N, int K) {
    constexpr int WTN = BN / 2;        // wave tile N
    constexpr int NJ  = WTN / 16;      // N frags per wave
    constexpr int NBC = BN / 64;       // B stage calls per wave

    __shared__ short sA[2][128 * 32];
    __shared__ short sB[2][BN * 32];

    const int tid  = threadIdx.x;
    const int lane = tid & 63;
    const int wave = tid >> 6;
    const int wm = wave >> 1, wn = wave & 1;

    // XCD-aware bijective swizzle (grid % 8 == 0)
    const int nwg = gridDim.x;
    const int swz = (blockIdx.x & 7) * (nwg >> 3) + (blockIdx.x >> 3);
    const int tiles_n = N / BN;
    const int m0 = (swz / tiles_n) * 128;
    const int n0 = (swz % tiles_n) * BN;

    f32x4 acc[4][NJ];
    #pragma unroll
    for (int i = 0; i < 4; ++i)
        #pragma unroll
        for (int j = 0; j < NJ; ++j) acc[i][j] = (f32x4){0.f, 0.f, 0.f, 0.f};

    const int r = lane & 15;
    const int G = lane >> 4;           // 0..3 (BK=32: 4 granules/row)

    // stage: granule ga -> row = ga>>2, lcol = ga&3, source col = lcol ^ (row&3)
    #define GSTAGE(kt_, buf_)                                                          \
        {                                                                              \
            _Pragma("unroll")                                                          \
            for (int i = 0; i < 2; ++i) {                                              \
                int ga = (i * 4 + wave) * 64 + lane;                                   \
                int row = ga >> 2, gcol = (ga & 3) ^ (row & 3);                        \
                gload_lds16(A + (size_t)(m0 + row) * K + (kt_) + gcol * 8,             \
                            &sA[buf_][(i * 4 + wave) * 512]);                          \
            }                                                                          \
            _Pragma("unroll")                                                          \
            for (int i = 0; i < NBC; ++i) {                                            \
                int gb = (i * 4 + wave) * 64 + lane;                                   \
                int row = gb >> 2, gcol = (gb & 3) ^ (row & 3);                        \
                gload_lds16(B + (size_t)(n0 + row) * K + (kt_) + gcol * 8,             \
                            &sB[buf_][(i * 4 + wave) * 512]);                          \
            }                                                                          \
        }

    GSTAGE(0, 0);
    __syncthreads();   // implicit vmcnt(0): tile 0 landed
    int cur = 0;

    const int nsteps = K >> 5;
    for (int ks = 0; ks < nsteps; ++ks) {
        if (ks + 1 < nsteps) GSTAGE((ks + 1) * 32, cur ^ 1);

        const int sg = G ^ (r & 3);    // swizzled granule for this lane's col-read
        bf16x8 af[4], bfr[NJ];
        #pragma unroll
        for (int i = 0; i < 4; ++i) {
            int row = wm * 64 + i * 16 + r;
            af[i] = *reinterpret_cast<const bf16x8*>(&sA[cur][row * 32 + sg * 8]);
        }
        #pragma unroll
        for (int j = 0; j < NJ; ++j) {
            int row = wn * WTN + j * 16 + r;
            bfr[j] = *reinterpret_cast<const bf16x8*>(&sB[cur][row * 32 + sg * 8]);
        }
        #pragma unroll
        for (int i = 0; i < 4; ++i)
            #pragma unroll
            for (int j = 0; j < NJ; ++j)
                acc[i][j] = __builtin_amdgcn_mfma_f32_16x16x32_bf16(af[i], bfr[j], acc[i][j], 0, 0, 0);

        __syncthreads();   // drains vmcnt(0): prefetch landed; cur free for overwrite
        cur ^= 1;
    }
    #undef GSTAGE

    // epilogue: D layout col=lane&15, row=4*(lane>>4)+reg
    const int col_l = lane & 15;
    const int row_g = (lane >> 4) * 4;
    #pragma unroll
    for (int i = 0; i < 4; ++i) {
        #pragma unroll
        for (int j = 0; j < NJ; ++j) {
            int nn = n0 + wn * WTN + j * 16 + col_l;
            float bv = bias[nn];
            float scl = (OUT_MODE == 2 && nn < HID) ? QSCL : 1.0f;
            #pragma unroll
            for (int reg = 0; reg < 4; ++reg) {
                int mm = m0 + wm * 64 + i * 16 + row_g + reg;
                float v = (acc[i][j][reg] + bv) * scl;
                if (OUT_MODE == 0) {
                    reinterpret_cast<float*>(Cout)[(size_t)mm * N + nn] = v;
                } else {
                    reinterpret_cast<unsigned short*>(Cout)[(size_t)mm * N + nn] = f2bf(v);
                }
            }
        }
    }
}

// ---------- transpose V part of qkv -> vT [bh][d][s] ----------
#define TLDP 72
__global__ __launch_bounds__(256) void transpose_v(const short* __restrict__ qkv,
                                                   short* __restrict__ vT) {
    const int st = blockIdx.x;   // s-tile (64 tokens)
    const int bh = blockIdx.y;
    const int b  = bh >> 4, h = bh & 15;
    __shared__ short ld[64 * TLDP];
    const int tid = threadIdx.x;

    #pragma unroll
    for (int i = 0; i < 2; ++i) {
        int idx = i * 256 + tid;          // 0..511
        int row = idx >> 3, c = idx & 7;
        int4 v = *reinterpret_cast<const int4*>(
            qkv + ((size_t)(b * SEQ + st * 64 + row)) * QKV_N + 2 * HID + h * DHEAD + c * 8);
        *reinterpret_cast<int4*>(&ld[row * TLDP + c * 8]) = v;
    }
    __syncthreads();
    #pragma unroll
    for (int i = 0; i < 4; ++i) {
        int idx = i * 256 + tid;          // 0..1023
        int d = idx >> 4, sc = idx & 15;  // d row, 4-token chunk
        ushort4 o;
        o.x = (unsigned short)ld[(sc * 4 + 0) * TLDP + d];
        o.y = (unsigned short)ld[(sc * 4 + 1) * TLDP + d];
        o.z = (unsigned short)ld[(sc * 4 + 2) * TLDP + d];
        o.w = (unsigned short)ld[(sc * 4 + 3) * TLDP + d];
        *reinterpret_cast<ushort4*>(&vT[((size_t)(bh * DHEAD + d)) * SEQ + st * 64 + sc * 4]) = o;
    }
}

// ---------- flash attention (causal), bf16 MFMA, no-max softmax ----------
// grid (32, 32): qt = (31 - x + y) & 31. Block = 128 threads = 2 waves, each wave
// 32 q-rows. KV tile = 64, double-buffered LDS via global_load_lds (source-swizzled).
#define SWZ(g_, row_) ((g_) ^ ((row_) & 7))

__global__ __launch_bounds__(128, 2) void attn_fwd(const short* __restrict__ qkv,
                                                   const short* __restrict__ vT,
                                                   short* __restrict__ av) {
    const int bh = blockIdx.y;
    const int b  = bh >> 4;
    const int h  = bh & 15;
    const int qt = (31 - blockIdx.x + blockIdx.y) & 31;

    __shared__ short sK [2][64 * 64];   // [buf][kv][d]   linear, source-swizzled
    __shared__ short sVT[2][64 * 64];   // [buf][d][kv]   linear, source-swizzled
    __shared__ short sP [2][32 * 64];   // [wave][row][kv] swizzled columns

    const int tid  = threadIdx.x;          // 0..127
    const int lane = tid & 63;
    const int wave = tid >> 6;
    const int r    = lane & 15;
    const int G    = lane >> 4;
    const int row_g = G * 4;

    const int qbw = qt * 64 + wave * 32;

    // Q fragments (pre-scaled by QSCL in the GEMM epilogue)
    bf16x8 qf[2][2];
    #pragma unroll
    for (int mi = 0; mi < 2; ++mi) {
        const short* Qg = qkv + ((size_t)(b * SEQ + qbw + mi * 16 + r)) * QKV_N + h * DHEAD;
        qf[mi][0] = *reinterpret_cast<const bf16x8*>(Qg + G * 8);
        qf[mi][1] = *reinterpret_cast<const bf16x8*>(Qg + 32 + G * 8);
    }

    f32x4 oacc[2][4];
    f32x4 oL[2];
    #pragma unroll
    for (int mi = 0; mi < 2; ++mi) {
        oL[mi] = (f32x4){0.f, 0.f, 0.f, 0.f};
        #pragma unroll
        for (int dg = 0; dg < 4; ++dg) oacc[mi][dg] = (f32x4){0.f, 0.f, 0.f, 0.f};
    }

    bf16x8 ones;
    #pragma unroll
    for (int e = 0; e < 8; ++e) ones[e] = (short)0x3f80;   // bf16 1.0

    const int lrow = lane >> 3;   // row offset within 8-row lane group
    const int lsg  = lane & 7;    // linear granule within row

    #define STAGE(kv0_, buf_)                                                              \
        {                                                                                  \
            _Pragma("unroll")                                                              \
            for (int i = 0; i < 4; ++i) {                                                  \
                int row  = i * 16 + wave * 8 + lrow;                                       \
                int srcg = lsg ^ (row & 7);                                                \
                gload_lds16(qkv + (size_t)(b * SEQ + (kv0_) + row) * QKV_N                 \
                                + HID + h * DHEAD + srcg * 8,                              \
                            &sK[buf_][(i * 128 + wave * 64) * 8]);                         \
                gload_lds16(vT + (size_t)(bh * DHEAD + row) * SEQ + (kv0_) + srcg * 8,     \
                            &sVT[buf_][(i * 128 + wave * 64) * 8]);                        \
            }                                                                              \
        }

    STAGE(0, 0);
    __syncthreads();   // implicit vmcnt(0) drain: tile 0 landed
    int cur = 0;

    for (int t = 0; t <= qt; ++t) {
        if (t < qt) STAGE((t + 1) * 64, cur ^ 1);   // async prefetch, no wait

        // K fragments (swizzled read)
        bf16x8 kb[4][2];
        #pragma unroll
        for (int g = 0; g < 4; ++g) {
            int row = g * 16 + r;
            kb[g][0] = *reinterpret_cast<const bf16x8*>(&sK[cur][row * 64 + SWZ(G, row) * 8]);
            kb[g][1] = *reinterpret_cast<const bf16x8*>(&sK[cur][row * 64 + SWZ(4 + G, row) * 8]);
        }

        const bool diag = (t == qt);

        #pragma unroll
        for (int mi = 0; mi < 2; ++mi) {
            f32x4 s[4];
            #pragma unroll
            for (int g = 0; g < 4; ++g) {
                f32x4 z = (f32x4){0.f, 0.f, 0.f, 0.f};
                z = __builtin_amdgcn_mfma_f32_16x16x32_bf16(qf[mi][0], kb[g][0], z, 0, 0, 0);
                z = __builtin_amdgcn_mfma_f32_16x16x32_bf16(qf[mi][1], kb[g][1], z, 0, 0, 0);
                s[g] = z;
            }
            if (diag) {
                #pragma unroll
                for (int g = 0; g < 4; ++g) {
                    #pragma unroll
                    for (int reg = 0; reg < 4; ++reg) {
                        int kvg = g * 16 + r;                        // D col = lane&15
                        int qg  = wave * 32 + mi * 16 + row_g + reg; // D row (within q-tile)
                        if (kvg > qg) s[g][reg] = -30000.f;
                    }
                }
            }
            // P = exp2(S) -> bf16 -> sP, column-granule swizzled
            #pragma unroll
            for (int g = 0; g < 4; ++g) {
                int gc = g * 2 + (r >> 3);     // linear granule of column g*16+r
                #pragma unroll
                for (int reg = 0; reg < 4; ++reg) {
                    float p = __builtin_amdgcn_exp2f(s[g][reg]);
                    int row = mi * 16 + row_g + reg;
                    sP[wave][row * 64 + SWZ(gc, row) * 8 + (r & 7)] = (short)f2bf(p);
                }
            }
        }

        asm volatile("s_waitcnt lgkmcnt(0)" ::: "memory");
        __builtin_amdgcn_sched_barrier(0);

        // V fragments (swizzled read)
        bf16x8 vb[4][2];
        #pragma unroll
        for (int dg = 0; dg < 4; ++dg) {
            int row = dg * 16 + r;
            vb[dg][0] = *reinterpret_cast<const bf16x8*>(&sVT[cur][row * 64 + SWZ(G, row) * 8]);
            vb[dg][1] = *reinterpret_cast<const bf16x8*>(&sVT[cur][row * 64 + SWZ(4 + G, row) * 8]);
        }

        #pragma unroll
        for (int mi = 0; mi < 2; ++mi) {
            int prow = mi * 16 + r;
            bf16x8 pa0 = *reinterpret_cast<const bf16x8*>(&sP[wave][prow * 64 + SWZ(G, prow) * 8]);
            bf16x8 pa1 = *reinterpret_cast<const bf16x8*>(&sP[wave][prow * 64 + SWZ(4 + G, prow) * 8]);
            #pragma unroll
            for (int dg = 0; dg < 4; ++dg) {
                oacc[mi][dg] = __builtin_amdgcn_mfma_f32_16x16x32_bf16(pa0, vb[dg][0], oacc[mi][dg], 0, 0, 0);
                oacc[mi][dg] = __builtin_amdgcn_mfma_f32_16x16x32_bf16(pa1, vb[dg][1], oacc[mi][dg], 0, 0, 0);
            }
            oL[mi] = __builtin_amdgcn_mfma_f32_16x16x32_bf16(pa0, ones, oL[mi], 0, 0, 0);
            oL[mi] = __builtin_amdgcn_mfma_f32_16x16x32_bf16(pa1, ones, oL[mi], 0, 0, 0);
        }

        __syncthreads();   // implicit vmcnt drain: next tile landed; sK/sVT[cur] free
        cur ^= 1;
    }

    // normalize and write AV (bf16)
    #pragma unroll
    for (int mi = 0; mi < 2; ++mi) {
        float il[4];
        #pragma unroll
        for (int reg = 0; reg < 4; ++reg) il[reg] = 1.0f / oL[mi][reg];
        #pragma unroll
        for (int dg = 0; dg < 4; ++dg) {
            #pragma unroll
            for (int reg = 0; reg < 4; ++reg) {
                float v = oacc[mi][dg][reg] * il[reg];
                size_t tok = (size_t)(b * SEQ + qbw + mi * 16 + row_g + reg);
                av[tok * HID + h * DHEAD + dg * 16 + r] = (short)f2bf(v);
            }
        }
    }
}

extern "C" void kernel_launch(void* const* d_in, const int* in_sizes, int n_in,
                              void* d_out, int out_size, void* d_ws, size_t ws_size,
                              hipStream_t stream) {
    const float* x     = (const float*)d_in[0];
    const float* W_qkv = (const float*)d_in[1];
    const float* b_qkv = (const float*)d_in[2];
    const float* W_o   = (const float*)d_in[3];
    const float* b_o   = (const float*)d_in[4];
    float* out = (float*)d_out;

    const int n_x    = NTOK * HID;
    const int n_wqkv = QKV_N * HID;
    const int n_wo   = HID * HID;
    const int n_qkv  = NTOK * QKV_N;
    const int n_av   = NTOK * HID;

    short* xb    = (short*)d_ws;
    short* wqkvb = xb + n_x;
    short* wob   = wqkvb + n_wqkv;
    short* qkv   = wob + n_wo;
    short* av    = qkv + n_qkv;
    short* vT    = av + n_av;

    cast_f32_bf16<<<n_x / 1024,    256, 0, stream>>>(x,     (unsigned short*)xb,    n_x / 4);
    cast_f32_bf16<<<n_wqkv / 1024, 256, 0, stream>>>(W_qkv, (unsigned short*)wqkvb, n_wqkv / 4);
    cast_f32_bf16<<<n_wo / 1024,   256, 0, stream>>>(W_o,   (unsigned short*)wob,   n_wo / 4);

    // qkv = x @ W_qkv^T + b_qkv  -> bf16 [4096][3072], Q columns pre-scaled by QSCL
    // grid 768 = (4096/128)*(3072/128), 1D with XCD swizzle
    gemm_bt<128, 2><<<(NTOK / 128) * (QKV_N / 128), 256, 0, stream>>>(
        xb, wqkvb, b_qkv, (void*)qkv, NTOK, QKV_N, HID);

    // vT [32 bh][64 d][2048 s]
    transpose_v<<<dim3(SEQ / 64, BATCH * NHEAD), 256, 0, stream>>>(qkv, vT);

    // attention -> av bf16 [4096][1024]
    attn_fwd<<<dim3(32, 32), 128, 0, stream>>>(qkv, vT, av);

    // out = av @ W_o^T + b_o  -> fp32; grid 512 = (4096/128)*(1024/64)
    gemm_bt<64, 0><<<(NTOK / 128) * (HID / 64), 256, 0, stream>>>(
        av, wob, b_o, (void*)out, NTOK, HID, HID);
}